// Round 1
// baseline (639.804 us; speedup 1.0000x reference)
//
#include <hip/hip_runtime.h>
#include <stdint.h>
#include <math.h>

typedef unsigned long long u64;
typedef long long ll;

#define H_    56
#define W_    56
#define HW_   3136
#define N_    64
#define C_    256
#define P_    64
#define NPIX_ 200704          // N_*HW_
#define BN_EPS 1e-5

// ---------------------------------------------------------------- weights ---
__global__ __launch_bounds__(256) void pack_weights_k(
    const float* __restrict__ w1, const float* __restrict__ w2,
    const float* __restrict__ w3,
    u64* __restrict__ ws1, u64* __restrict__ wn1,
    u64* __restrict__ ws2, u64* __restrict__ wn2, int* __restrict__ b2,
    u64* __restrict__ ws3, u64* __restrict__ wn3, int* __restrict__ b3) {
  int t = blockIdx.x * 256 + threadIdx.x;
  if (t < 64) {                       // w1: [64][256] -> 4 chunks of 64
    int co = t;
    for (int ch = 0; ch < 4; ++ch) {
      u64 s = 0, n = 0;
      for (int j = 0; j < 64; ++j) {
        float v = w1[co * 256 + ch * 64 + j];
        s |= ((u64)(v < 0.f)) << j;
        n |= ((u64)(v != 0.f)) << j;
      }
      ws1[co * 4 + ch] = s; wn1[co * 4 + ch] = n;
    }
  } else if (t < 64 + 576) {          // w2: [64][64][3][3] per (co,tap)
    int idx = t - 64, co = idx / 9, tap = idx % 9;
    u64 s = 0, n = 0;
    for (int ci = 0; ci < 64; ++ci) {
      float v = w2[(co * 64 + ci) * 9 + tap];
      s |= ((u64)(v < 0.f)) << ci;
      n |= ((u64)(v != 0.f)) << ci;
    }
    ws2[idx] = s; wn2[idx] = n; b2[idx] = __popcll(n);
  } else if (t < 64 + 576 + 256) {    // w3: [256][64]
    int co = t - 640;
    u64 s = 0, n = 0;
    for (int ci = 0; ci < 64; ++ci) {
      float v = w3[co * 64 + ci];
      s |= ((u64)(v < 0.f)) << ci;
      n |= ((u64)(v != 0.f)) << ci;
    }
    ws3[co] = s; wn3[co] = n; b3[co] = __popcll(n);
  }
}

// --------------------------------------------------------------- pack x -----
// x: NCHW fp32. Per pixel, pack 256 channels into 4 sign u64 + 4 nonzero u64.
__global__ __launch_bounds__(256) void pack_x_k(
    const float* __restrict__ x, u64* __restrict__ xs, u64* __restrict__ xn) {
  int p = blockIdx.x * 256 + threadIdx.x;         // 784 blocks -> NPIX_
  int n = p / HW_, hw = p % HW_;
  const float* xb = x + (size_t)n * C_ * HW_ + hw;
  for (int ch = 0; ch < 4; ++ch) {
    u64 s = 0, nb = 0;
    for (int j = 0; j < 64; ++j) {
      float v = xb[(size_t)(ch * 64 + j) * HW_];
      s |= ((u64)(v < 0.f)) << j;
      nb |= ((u64)(v != 0.f)) << j;
    }
    xs[(size_t)p * 4 + ch] = s;
    xn[(size_t)p * 4 + ch] = nb;
  }
}

// --------------------------------------------------------------- conv1 ------
// 1x1, Cin=256 (4 u64 pairs), Cout=64. Block (64 co, 4 px). 256 px/block.
__global__ __launch_bounds__(256) void conv1_k(
    const u64* __restrict__ xs, const u64* __restrict__ xn,
    const u64* __restrict__ ws1, const u64* __restrict__ wn1,
    short* __restrict__ y, u64* __restrict__ gsum, u64* __restrict__ gsq) {
  __shared__ u64 lws[256], lwn[256];
  __shared__ int reds[4][64], redq[4][64];
  int tx = threadIdx.x, ty = threadIdx.y, lidx = ty * 64 + tx;
  lws[lidx] = ws1[lidx]; lwn[lidx] = wn1[lidx];
  __syncthreads();
  int s_acc = 0, q_acc = 0;
  int base = blockIdx.x * 256;
  for (int i = 0; i < 64; ++i) {
    int p = base + i * 4 + ty;
    u64 s0 = xs[(size_t)p*4+0], s1 = xs[(size_t)p*4+1],
        s2 = xs[(size_t)p*4+2], s3 = xs[(size_t)p*4+3];
    u64 n0 = xn[(size_t)p*4+0], n1 = xn[(size_t)p*4+1],
        n2 = xn[(size_t)p*4+2], n3 = xn[(size_t)p*4+3];
    int acc = 0;
    {
      u64 v, a;
      v = n0 & lwn[tx*4+0]; a = ~(s0 ^ lws[tx*4+0]) & v; acc += 2*__popcll(a) - __popcll(v);
      v = n1 & lwn[tx*4+1]; a = ~(s1 ^ lws[tx*4+1]) & v; acc += 2*__popcll(a) - __popcll(v);
      v = n2 & lwn[tx*4+2]; a = ~(s2 ^ lws[tx*4+2]) & v; acc += 2*__popcll(a) - __popcll(v);
      v = n3 & lwn[tx*4+3]; a = ~(s3 ^ lws[tx*4+3]) & v; acc += 2*__popcll(a) - __popcll(v);
    }
    y[(size_t)p * 64 + tx] = (short)acc;
    s_acc += acc; q_acc += acc * acc;
  }
  reds[ty][tx] = s_acc; redq[ty][tx] = q_acc;
  __syncthreads();
  if (ty == 0) {
    int s = reds[0][tx] + reds[1][tx] + reds[2][tx] + reds[3][tx];
    int q = redq[0][tx] + redq[1][tx] + redq[2][tx] + redq[3][tx];
    atomicAdd(&gsum[tx], (u64)(ll)s);
    atomicAdd(&gsq[tx],  (u64)(ll)q);
  }
}

// ------------------------------------------------------------- finalize -----
__global__ void finalize_bn_k(const u64* __restrict__ gsum,
                              const u64* __restrict__ gsq,
                              const float* __restrict__ gamma,
                              const float* __restrict__ beta,
                              double* __restrict__ dsc, double* __restrict__ dsh,
                              int ch) {
  int c = blockIdx.x * blockDim.x + threadIdx.x;
  if (c < ch) {
    double S = (double)(ll)gsum[c], Q = (double)(ll)gsq[c];
    double mean = S / (double)NPIX_;
    double var  = Q / (double)NPIX_ - mean * mean;
    double inv  = 1.0 / sqrt(var + BN_EPS);
    double sc   = (double)gamma[c] * inv;
    dsc[c] = sc;
    dsh[c] = (double)beta[c] - mean * sc;
  }
}

// -------------------------------------------------------- binarize+pack -----
// wave = 64 lanes <-> 64 channels; ballot builds one u64 bitplane per pixel.
__global__ __launch_bounds__(256) void binarize_pack_k(
    const short* __restrict__ y, const double* __restrict__ dsc,
    const double* __restrict__ dsh, u64* __restrict__ pout) {
  int lane = threadIdx.x & 63, wid = threadIdx.x >> 6;
  double sc = dsc[lane], sh = dsh[lane];
  int base = blockIdx.x * 256;
  for (int i = 0; i < 64; ++i) {
    int p = base + i * 4 + wid;
    int v = (int)y[(size_t)p * 64 + lane];
    u64 m = __ballot(sc * (double)v + sh < 0.0);   // bit=1 means negative
    if (lane == 0) pout[p] = m;
  }
}

// --------------------------------------------------------------- conv2 ------
// 3x3 pad=1, Cin=Cout=64. Block (64 co, 4 px). Zero-padded taps contribute 0.
__global__ __launch_bounds__(256) void conv2_k(
    const u64* __restrict__ p1,
    const u64* __restrict__ ws2, const u64* __restrict__ wn2,
    const int* __restrict__ b2,
    short* __restrict__ y, u64* __restrict__ gsum, u64* __restrict__ gsq) {
  __shared__ u64 lws[576], lwn[576];
  __shared__ int lb[576];
  __shared__ int reds[4][64], redq[4][64];
  int tx = threadIdx.x, ty = threadIdx.y, lidx = ty * 64 + tx;
  for (int j = lidx; j < 576; j += 256) { lws[j] = ws2[j]; lwn[j] = wn2[j]; lb[j] = b2[j]; }
  __syncthreads();
  int s_acc = 0, q_acc = 0;
  int base = blockIdx.x * 256;
  for (int i = 0; i < 64; ++i) {
    int p = base + i * 4 + ty;
    int n = p / HW_, hw = p % HW_, h = hw / W_, w = hw % W_;
    u64 tv[9]; bool ok[9];
    #pragma unroll
    for (int dh = -1; dh <= 1; ++dh)
      #pragma unroll
      for (int dw = -1; dw <= 1; ++dw) {
        int k = (dh + 1) * 3 + (dw + 1);
        int h2 = h + dh, w2c = w + dw;
        bool v = (h2 >= 0) & (h2 < H_) & (w2c >= 0) & (w2c < W_);
        ok[k] = v;
        tv[k] = v ? p1[n * HW_ + h2 * W_ + w2c] : 0ULL;
      }
    int acc = 0;
    #pragma unroll
    for (int k = 0; k < 9; ++k) {
      int wi = tx * 9 + k;
      u64 a = ~(tv[k] ^ lws[wi]) & lwn[wi];
      int d = 2 * __popcll(a) - lb[wi];
      acc += ok[k] ? d : 0;
    }
    y[(size_t)p * 64 + tx] = (short)acc;
    s_acc += acc; q_acc += acc * acc;
  }
  reds[ty][tx] = s_acc; redq[ty][tx] = q_acc;
  __syncthreads();
  if (ty == 0) {
    int s = reds[0][tx] + reds[1][tx] + reds[2][tx] + reds[3][tx];
    int q = redq[0][tx] + redq[1][tx] + redq[2][tx] + redq[3][tx];
    atomicAdd(&gsum[tx], (u64)(ll)s);
    atomicAdd(&gsq[tx],  (u64)(ll)q);
  }
}

// ---------------------------------------------------------- conv3 stats -----
// 1x1, Cin=64 (1 u64), Cout=256. thread <-> co, loop 256 px/block.
__global__ __launch_bounds__(256) void conv3_stats_k(
    const u64* __restrict__ p2,
    const u64* __restrict__ ws3, const u64* __restrict__ wn3,
    const int* __restrict__ b3,
    u64* __restrict__ gsum, u64* __restrict__ gsq) {
  int t = threadIdx.x;                 // co
  u64 s3 = ws3[t], n3 = wn3[t];
  int bb = b3[t];
  int s = 0, q = 0;
  int base = blockIdx.x * 256;
  for (int i = 0; i < 256; ++i) {
    u64 m = p2[base + i];
    int yv = 2 * __popcll(~(m ^ s3) & n3) - bb;
    s += yv; q += yv * yv;
  }
  atomicAdd(&gsum[t], (u64)(ll)s);
  atomicAdd(&gsq[t],  (u64)(ll)q);
}

// --------------------------------------------------------------- final ------
// out = hardtanh(bn3(conv3) + x), recomputing conv3 on the fly. float4 I/O.
__global__ __launch_bounds__(256) void final_k(
    const float* __restrict__ x, const u64* __restrict__ p2,
    const u64* __restrict__ ws3, const u64* __restrict__ wn3,
    const int* __restrict__ b3,
    const double* __restrict__ dsc3, const double* __restrict__ dsh3,
    float* __restrict__ out) {
  size_t i4 = (size_t)blockIdx.x * 256 + threadIdx.x;   // group of 4 elements
  size_t idx = i4 * 4;
  int co = (int)((idx / HW_) % C_);
  int nn = (int)(idx / ((size_t)HW_ * C_));
  int hw = (int)(idx % HW_);
  int pb = nn * HW_ + hw;
  u64 s3 = ws3[co], n3 = wn3[co];
  int bb = b3[co];
  float sc = (float)dsc3[co], sh = (float)dsh3[co];
  float4 xv = *(const float4*)(x + idx);
  float4 ov;
  {
    int y0 = 2 * __popcll(~(p2[pb + 0] ^ s3) & n3) - bb;
    int y1 = 2 * __popcll(~(p2[pb + 1] ^ s3) & n3) - bb;
    int y2 = 2 * __popcll(~(p2[pb + 2] ^ s3) & n3) - bb;
    int y3 = 2 * __popcll(~(p2[pb + 3] ^ s3) & n3) - bb;
    ov.x = fminf(fmaxf(sc * (float)y0 + sh + xv.x, -1.f), 1.f);
    ov.y = fminf(fmaxf(sc * (float)y1 + sh + xv.y, -1.f), 1.f);
    ov.z = fminf(fmaxf(sc * (float)y2 + sh + xv.z, -1.f), 1.f);
    ov.w = fminf(fmaxf(sc * (float)y3 + sh + xv.w, -1.f), 1.f);
  }
  *(float4*)(out + idx) = ov;
}

// ---------------------------------------------------------------- launch ----
extern "C" void kernel_launch(void* const* d_in, const int* in_sizes, int n_in,
                              void* d_out, int out_size, void* d_ws, size_t ws_size,
                              hipStream_t stream) {
  const float* x  = (const float*)d_in[0];
  const float* w1 = (const float*)d_in[1];
  const float* w2 = (const float*)d_in[2];
  const float* w3 = (const float*)d_in[3];
  const float* g1 = (const float*)d_in[4];
  const float* b1 = (const float*)d_in[5];
  const float* g2 = (const float*)d_in[6];
  const float* b2 = (const float*)d_in[7];
  const float* g3 = (const float*)d_in[8];
  const float* b3 = (const float*)d_in[9];
  float* out = (float*)d_out;

  char* base = (char*)d_ws;
  size_t off = 0;
  auto alloc = [&](size_t bytes) -> char* {
    char* p = base + off;
    off = (off + bytes + 255) & ~(size_t)255;
    return p;
  };
  u64* xs   = (u64*)alloc((size_t)NPIX_ * 4 * 8);
  u64* xn   = (u64*)alloc((size_t)NPIX_ * 4 * 8);
  u64* p1   = (u64*)alloc((size_t)NPIX_ * 8);
  u64* p2   = (u64*)alloc((size_t)NPIX_ * 8);
  short* yb = (short*)alloc((size_t)NPIX_ * 64 * 2);   // reused for y1 and y2
  u64* ws1  = (u64*)alloc(256 * 8);
  u64* wn1  = (u64*)alloc(256 * 8);
  u64* ws2  = (u64*)alloc(576 * 8);
  u64* wn2  = (u64*)alloc(576 * 8);
  int* bb2  = (int*)alloc(576 * 4);
  u64* ws3  = (u64*)alloc(256 * 8);
  u64* wn3  = (u64*)alloc(256 * 8);
  int* bb3  = (int*)alloc(256 * 4);
  // contiguous stats block (zeroed each call)
  char* stats = alloc(768 * 8);
  u64* sum1 = (u64*)stats;          u64* sq1 = sum1 + 64;
  u64* sum2 = sq1 + 64;             u64* sq2 = sum2 + 64;
  u64* sum3 = sq2 + 64;             u64* sq3 = sum3 + 256;
  double* dsc1 = (double*)alloc(64 * 8);
  double* dsh1 = (double*)alloc(64 * 8);
  double* dsc2 = (double*)alloc(64 * 8);
  double* dsh2 = (double*)alloc(64 * 8);
  double* dsc3 = (double*)alloc(256 * 8);
  double* dsh3 = (double*)alloc(256 * 8);
  (void)ws_size; (void)n_in; (void)in_sizes; (void)out_size;

  hipMemsetAsync(stats, 0, 768 * 8, stream);

  pack_weights_k<<<4, 256, 0, stream>>>(w1, w2, w3, ws1, wn1, ws2, wn2, bb2,
                                        ws3, wn3, bb3);
  pack_x_k<<<784, 256, 0, stream>>>(x, xs, xn);

  dim3 blk(64, 4);
  conv1_k<<<784, blk, 0, stream>>>(xs, xn, ws1, wn1, yb, sum1, sq1);
  finalize_bn_k<<<1, 64, 0, stream>>>(sum1, sq1, g1, b1, dsc1, dsh1, 64);
  binarize_pack_k<<<784, 256, 0, stream>>>(yb, dsc1, dsh1, p1);

  conv2_k<<<784, blk, 0, stream>>>(p1, ws2, wn2, bb2, yb, sum2, sq2);
  finalize_bn_k<<<1, 64, 0, stream>>>(sum2, sq2, g2, b2, dsc2, dsh2, 64);
  binarize_pack_k<<<784, 256, 0, stream>>>(yb, dsc2, dsh2, p2);

  conv3_stats_k<<<784, 256, 0, stream>>>(p2, ws3, wn3, bb3, sum3, sq3);
  finalize_bn_k<<<1, 256, 0, stream>>>(sum3, sq3, g3, b3, dsc3, dsh3, 256);

  final_k<<<50176, 256, 0, stream>>>(x, p2, ws3, wn3, bb3, dsc3, dsh3, out);
}

// Round 2
// 613.930 us; speedup vs baseline: 1.0421x; 1.0421x over previous
//
#include <hip/hip_runtime.h>
#include <stdint.h>
#include <math.h>

typedef unsigned long long u64;
typedef long long ll;

#define H_    56
#define W_    56
#define HW_   3136
#define N_    64
#define C_    256
#define P_    64
#define NPIX_ 200704          // N_*HW_
#define BN_EPS 1e-5

// ---------------------------------------------------------------- weights ---
__global__ __launch_bounds__(256) void pack_weights_k(
    const float* __restrict__ w1, const float* __restrict__ w2,
    const float* __restrict__ w3,
    u64* __restrict__ ws1, u64* __restrict__ wn1,
    u64* __restrict__ ws2, u64* __restrict__ wn2, int* __restrict__ b2,
    u64* __restrict__ ws3, u64* __restrict__ wn3, int* __restrict__ b3) {
  int t = blockIdx.x * 256 + threadIdx.x;
  if (t < 64) {                       // w1: [64][256] -> 4 chunks of 64
    int co = t;
    for (int ch = 0; ch < 4; ++ch) {
      u64 s = 0, n = 0;
      for (int j = 0; j < 64; ++j) {
        float v = w1[co * 256 + ch * 64 + j];
        s |= ((u64)(v < 0.f)) << j;
        n |= ((u64)(v != 0.f)) << j;
      }
      ws1[co * 4 + ch] = s; wn1[co * 4 + ch] = n;
    }
  } else if (t < 64 + 576) {          // w2: [64][64][3][3] per (co,tap)
    int idx = t - 64, co = idx / 9, tap = idx % 9;
    u64 s = 0, n = 0;
    for (int ci = 0; ci < 64; ++ci) {
      float v = w2[(co * 64 + ci) * 9 + tap];
      s |= ((u64)(v < 0.f)) << ci;
      n |= ((u64)(v != 0.f)) << ci;
    }
    ws2[idx] = s; wn2[idx] = n; b2[idx] = __popcll(n);
  } else if (t < 64 + 576 + 256) {    // w3: [256][64]
    int co = t - 640;
    u64 s = 0, n = 0;
    for (int ci = 0; ci < 64; ++ci) {
      float v = w3[co * 64 + ci];
      s |= ((u64)(v < 0.f)) << ci;
      n |= ((u64)(v != 0.f)) << ci;
    }
    ws3[co] = s; wn3[co] = n; b3[co] = __popcll(n);
  }
}

// -------------------------------------------- fused pack_x + conv1 + stats --
// thread = pixel. Pack 256 channels (coalesced across lanes), then 64 co
// XNOR-popcounts with LDS-broadcast weights. y1 stored transposed [co][px].
__global__ __launch_bounds__(256) void fused1_k(
    const float* __restrict__ x,
    const u64* __restrict__ ws1, const u64* __restrict__ wn1,
    short* __restrict__ y1, u64* __restrict__ gsum, u64* __restrict__ gsq) {
  __shared__ u64 lws[256], lwn[256];
  __shared__ int ssum[64], ssq[64];
  int tid = threadIdx.x;
  lws[tid] = ws1[tid]; lwn[tid] = wn1[tid];
  if (tid < 64) { ssum[tid] = 0; ssq[tid] = 0; }
  __syncthreads();

  int p = blockIdx.x * 256 + tid;
  int n = p / HW_, hw = p % HW_;
  const float* xb = x + (size_t)n * (C_ * HW_) + hw;
  u64 s[4], nb[4];
  #pragma unroll
  for (int ch = 0; ch < 4; ++ch) {
    u64 sv = 0, nv = 0;
    #pragma unroll
    for (int j = 0; j < 64; ++j) {
      float v = xb[(size_t)((ch * 64 + j) * HW_)];
      sv |= ((u64)(v < 0.f)) << j;
      nv |= ((u64)(v != 0.f)) << j;
    }
    s[ch] = sv; nb[ch] = nv;
  }

  int lane = tid & 63;
  for (int co = 0; co < 64; ++co) {
    int acc = 0;
    #pragma unroll
    for (int ch = 0; ch < 4; ++ch) {
      u64 v = nb[ch] & lwn[co * 4 + ch];
      u64 a = ~(s[ch] ^ lws[co * 4 + ch]) & v;
      acc += 2 * __popcll(a) - __popcll(v);
    }
    y1[(size_t)co * NPIX_ + p] = (short)acc;
    int rs = acc, rq = acc * acc;
    #pragma unroll
    for (int m = 32; m; m >>= 1) {
      rs += __shfl_xor(rs, m, 64);
      rq += __shfl_xor(rq, m, 64);
    }
    if (lane == 0) { atomicAdd(&ssum[co], rs); atomicAdd(&ssq[co], rq); }
  }
  __syncthreads();
  if (tid < 64) {
    atomicAdd(&gsum[tid], (u64)(ll)ssum[tid]);
    atomicAdd(&gsq[tid],  (u64)(ll)ssq[tid]);
  }
}

// -------------------------------------------------------- binarize+pack -----
// thread = pixel; thresholds computed in-block from raw stats. y is [co][px].
__global__ __launch_bounds__(256) void binpack_k(
    const short* __restrict__ y,
    const u64* __restrict__ gsum, const u64* __restrict__ gsq,
    const float* __restrict__ gamma, const float* __restrict__ beta,
    u64* __restrict__ pout) {
  __shared__ double tsc[64], tsh[64];
  int tid = threadIdx.x;
  if (tid < 64) {
    double S = (double)(ll)gsum[tid], Q = (double)(ll)gsq[tid];
    double mean = S / (double)NPIX_;
    double var  = Q / (double)NPIX_ - mean * mean;
    double inv  = 1.0 / sqrt(var + BN_EPS);
    double sc   = (double)gamma[tid] * inv;
    tsc[tid] = sc;
    tsh[tid] = (double)beta[tid] - mean * sc;
  }
  __syncthreads();
  int p = blockIdx.x * 256 + tid;
  u64 m = 0;
  #pragma unroll 8
  for (int co = 0; co < 64; ++co) {
    int v = (int)y[(size_t)co * NPIX_ + p];
    m |= ((u64)(tsc[co] * (double)v + tsh[co] < 0.0)) << co;
  }
  pout[p] = m;
}

// --------------------------------------------------------------- conv2 ------
// 3x3 pad=1. thread = pixel; 9 neighborhood words in registers; weights
// broadcast from LDS; stats inlined via wave reduction.
__global__ __launch_bounds__(256) void conv2_k(
    const u64* __restrict__ p1,
    const u64* __restrict__ ws2, const u64* __restrict__ wn2,
    const int* __restrict__ b2,
    short* __restrict__ y2, u64* __restrict__ gsum, u64* __restrict__ gsq) {
  __shared__ u64 lws[576], lwn[576];
  __shared__ int lb[576];
  __shared__ int ssum[64], ssq[64];
  int tid = threadIdx.x;
  for (int j = tid; j < 576; j += 256) { lws[j] = ws2[j]; lwn[j] = wn2[j]; lb[j] = b2[j]; }
  if (tid < 64) { ssum[tid] = 0; ssq[tid] = 0; }
  __syncthreads();

  int p = blockIdx.x * 256 + tid;
  int n = p / HW_, hw = p % HW_, h = hw / W_, w = hw % W_;
  u64 tv[9]; bool ok[9];
  #pragma unroll
  for (int dh = -1; dh <= 1; ++dh)
    #pragma unroll
    for (int dw = -1; dw <= 1; ++dw) {
      int k = (dh + 1) * 3 + (dw + 1);
      int h2 = h + dh, w2c = w + dw;
      bool v = (h2 >= 0) & (h2 < H_) & (w2c >= 0) & (w2c < W_);
      ok[k] = v;
      tv[k] = v ? p1[n * HW_ + h2 * W_ + w2c] : 0ULL;
    }

  int lane = tid & 63;
  for (int co = 0; co < 64; ++co) {
    int acc = 0;
    #pragma unroll
    for (int k = 0; k < 9; ++k) {
      int wi = co * 9 + k;
      u64 a = ~(tv[k] ^ lws[wi]) & lwn[wi];
      int d = 2 * __popcll(a) - lb[wi];
      acc += ok[k] ? d : 0;
    }
    y2[(size_t)co * NPIX_ + p] = (short)acc;
    int rs = acc, rq = acc * acc;
    #pragma unroll
    for (int m = 32; m; m >>= 1) {
      rs += __shfl_xor(rs, m, 64);
      rq += __shfl_xor(rq, m, 64);
    }
    if (lane == 0) { atomicAdd(&ssum[co], rs); atomicAdd(&ssq[co], rq); }
  }
  __syncthreads();
  if (tid < 64) {
    atomicAdd(&gsum[tid], (u64)(ll)ssum[tid]);
    atomicAdd(&gsq[tid],  (u64)(ll)ssq[tid]);
  }
}

// ---------------------------------------------------------- conv3 stats -----
// thread = co (256), uniform-broadcast pixel loads; 512 px per block.
__global__ __launch_bounds__(256) void conv3_stats_k(
    const u64* __restrict__ p2,
    const u64* __restrict__ ws3, const u64* __restrict__ wn3,
    const int* __restrict__ b3,
    u64* __restrict__ gsum, u64* __restrict__ gsq) {
  int t = threadIdx.x;                 // co
  u64 s3 = ws3[t], n3 = wn3[t];
  int bb = b3[t];
  int s = 0, q = 0;
  int base = blockIdx.x * 512;
  #pragma unroll 4
  for (int i = 0; i < 512; ++i) {
    u64 m = p2[base + i];
    int yv = 2 * __popcll(~(m ^ s3) & n3) - bb;
    s += yv; q += yv * yv;
  }
  atomicAdd(&gsum[t], (u64)(ll)s);
  atomicAdd(&gsq[t],  (u64)(ll)q);
}

// --------------------------------------------------------------- final ------
// out = hardtanh(bn3(conv3) + x); conv3 recomputed from p2; thresholds
// computed in-block (each block spans at most 2 channels). float4 I/O.
__global__ __launch_bounds__(256) void final_k(
    const float* __restrict__ x, const u64* __restrict__ p2,
    const u64* __restrict__ ws3, const u64* __restrict__ wn3,
    const int* __restrict__ b3,
    const u64* __restrict__ gsum, const u64* __restrict__ gsq,
    const float* __restrict__ gamma, const float* __restrict__ beta,
    float* __restrict__ out) {
  __shared__ float fsc[2], fsh[2];
  size_t base = (size_t)blockIdx.x * 1024;       // element base
  size_t r0 = base / HW_;                        // linear (n*C+co) index
  if (threadIdx.x < 2) {
    int c = (int)((r0 + threadIdx.x) % C_);
    double S = (double)(ll)gsum[c], Q = (double)(ll)gsq[c];
    double mean = S / (double)NPIX_;
    double var  = Q / (double)NPIX_ - mean * mean;
    double inv  = 1.0 / sqrt(var + BN_EPS);
    double sc   = (double)gamma[c] * inv;
    fsc[threadIdx.x] = (float)sc;
    fsh[threadIdx.x] = (float)((double)beta[c] - mean * sc);
  }
  __syncthreads();

  size_t idx = base + (size_t)threadIdx.x * 4;
  size_t lin = idx / HW_;
  int rr = (int)(lin - r0);                      // 0 or 1
  int co = (int)(lin % C_);
  int nn = (int)(lin / C_);
  int hw = (int)(idx % HW_);
  int pb = nn * HW_ + hw;
  u64 s3 = ws3[co], n3 = wn3[co];
  int bb = b3[co];
  float sc = fsc[rr], sh = fsh[rr];
  float4 xv = *(const float4*)(x + idx);
  float4 ov;
  int y0 = 2 * __popcll(~(p2[pb + 0] ^ s3) & n3) - bb;
  int y1 = 2 * __popcll(~(p2[pb + 1] ^ s3) & n3) - bb;
  int y2 = 2 * __popcll(~(p2[pb + 2] ^ s3) & n3) - bb;
  int y3 = 2 * __popcll(~(p2[pb + 3] ^ s3) & n3) - bb;
  ov.x = fminf(fmaxf(sc * (float)y0 + sh + xv.x, -1.f), 1.f);
  ov.y = fminf(fmaxf(sc * (float)y1 + sh + xv.y, -1.f), 1.f);
  ov.z = fminf(fmaxf(sc * (float)y2 + sh + xv.z, -1.f), 1.f);
  ov.w = fminf(fmaxf(sc * (float)y3 + sh + xv.w, -1.f), 1.f);
  *(float4*)(out + idx) = ov;
}

// ---------------------------------------------------------------- launch ----
extern "C" void kernel_launch(void* const* d_in, const int* in_sizes, int n_in,
                              void* d_out, int out_size, void* d_ws, size_t ws_size,
                              hipStream_t stream) {
  const float* x  = (const float*)d_in[0];
  const float* w1 = (const float*)d_in[1];
  const float* w2 = (const float*)d_in[2];
  const float* w3 = (const float*)d_in[3];
  const float* g1 = (const float*)d_in[4];
  const float* b1 = (const float*)d_in[5];
  const float* g2 = (const float*)d_in[6];
  const float* b2 = (const float*)d_in[7];
  const float* g3 = (const float*)d_in[8];
  const float* b3 = (const float*)d_in[9];
  float* out = (float*)d_out;

  char* base = (char*)d_ws;
  size_t off = 0;
  auto alloc = [&](size_t bytes) -> char* {
    char* p = base + off;
    off = (off + bytes + 255) & ~(size_t)255;
    return p;
  };
  short* y1b = (short*)alloc((size_t)NPIX_ * 64 * 2);  // [co][px], reused y2
  u64* p1   = (u64*)alloc((size_t)NPIX_ * 8);
  u64* p2   = (u64*)alloc((size_t)NPIX_ * 8);
  u64* ws1  = (u64*)alloc(256 * 8);
  u64* wn1  = (u64*)alloc(256 * 8);
  u64* ws2  = (u64*)alloc(576 * 8);
  u64* wn2  = (u64*)alloc(576 * 8);
  int* bb2  = (int*)alloc(576 * 4);
  u64* ws3  = (u64*)alloc(256 * 8);
  u64* wn3  = (u64*)alloc(256 * 8);
  int* bb3  = (int*)alloc(256 * 4);
  char* stats = alloc(768 * 8);                 // zeroed each call
  u64* sum1 = (u64*)stats;          u64* sq1 = sum1 + 64;
  u64* sum2 = sq1 + 64;             u64* sq2 = sum2 + 64;
  u64* sum3 = sq2 + 64;             u64* sq3 = sum3 + 256;
  (void)ws_size; (void)n_in; (void)in_sizes; (void)out_size;

  hipMemsetAsync(stats, 0, 768 * 8, stream);

  pack_weights_k<<<4, 256, 0, stream>>>(w1, w2, w3, ws1, wn1, ws2, wn2, bb2,
                                        ws3, wn3, bb3);

  fused1_k<<<784, 256, 0, stream>>>(x, ws1, wn1, y1b, sum1, sq1);
  binpack_k<<<784, 256, 0, stream>>>(y1b, sum1, sq1, g1, b1, p1);

  conv2_k<<<784, 256, 0, stream>>>(p1, ws2, wn2, bb2, y1b, sum2, sq2);
  binpack_k<<<784, 256, 0, stream>>>(y1b, sum2, sq2, g2, b2, p2);

  conv3_stats_k<<<392, 256, 0, stream>>>(p2, ws3, wn3, bb3, sum3, sq3);

  final_k<<<50176, 256, 0, stream>>>(x, p2, ws3, wn3, bb3, sum3, sq3, g3, b3,
                                     out);
}